// Round 1
// baseline (12789.397 us; speedup 1.0000x reference)
//
#include <hip/hip_runtime.h>
#include <hip/hip_bf16.h>
#include <math.h>

// Problem constants
#define B_  2
#define T_  512
#define C_  768
#define H_  12
#define V_  50304
#define L_  12
#define HD_ 64
#define M_  (B_*T_)          // 1024 rows of activations

#define EPI_NONE 0
#define EPI_GELU 1
#define EPI_RES  2
#define EPI_DIST 3

// ---------------- embedding ----------------
__global__ __launch_bounds__(256) void embed_k(const int* __restrict__ idx,
                                               const float* __restrict__ wte,
                                               const float* __restrict__ wpe,
                                               float* __restrict__ x)
{
    int row = blockIdx.x;            // 0..1023  (b*T + t)
    int t   = row & (T_-1);
    int tok = idx[row];
    const float* wt = wte + (size_t)tok * C_;
    const float* wp = wpe + (size_t)t   * C_;
    float* xr = x + (size_t)row * C_;
    for (int i = threadIdx.x; i < C_; i += 256)
        xr[i] = wt[i] + wp[i];
}

// ---------------- layernorm (block per row) ----------------
__global__ __launch_bounds__(256) void ln_k(const float* __restrict__ x,
                                            const float* __restrict__ w,
                                            const float* __restrict__ bb,
                                            float* __restrict__ out,
                                            float* __restrict__ xx_out)
{
    int row = blockIdx.x, tid = threadIdx.x;
    __shared__ float buf[C_];
    __shared__ float red[256];
    const float* xr = x + (size_t)row * C_;

    float ls = 0.f;
    for (int i = tid; i < C_; i += 256) { float v = xr[i]; buf[i] = v; ls += v; }
    red[tid] = ls; __syncthreads();
    for (int s = 128; s > 0; s >>= 1) { if (tid < s) red[tid] += red[tid+s]; __syncthreads(); }
    float mean = red[0] * (1.f / C_);
    __syncthreads();

    float lv = 0.f;
    for (int i = tid; i < C_; i += 256) { float d = buf[i] - mean; lv += d*d; }
    red[tid] = lv; __syncthreads();
    for (int s = 128; s > 0; s >>= 1) { if (tid < s) red[tid] += red[tid+s]; __syncthreads(); }
    float rstd = 1.0f / sqrtf(red[0] * (1.f / C_) + 1e-5f);
    __syncthreads();

    float lss = 0.f;
    float* orow = out + (size_t)row * C_;
    for (int i = tid; i < C_; i += 256) {
        float o = (buf[i] - mean) * rstd * w[i] + bb[i];
        orow[i] = o;
        lss += o * o;
    }
    if (xx_out) {
        red[tid] = lss; __syncthreads();
        for (int s = 128; s > 0; s >>= 1) { if (tid < s) red[tid] += red[tid+s]; __syncthreads(); }
        if (tid == 0) xx_out[row] = red[0];
    }
}

// ---------------- NT GEMM: C[m,n] = sum_k A[m,k]*Bw[n,k] (+epilogue) -------
// BM=BN=128, BK=16, 256 threads, 8x8 per thread. M,N %128==0, K %16==0.
__device__ __forceinline__ float gelu_f(float t) {
    return 0.5f * t * (1.0f + tanhf(0.7978845608028654f * (t + 0.044715f * t * t * t)));
}

__global__ __launch_bounds__(256) void gemm_nt(const float* __restrict__ A,
                                               const float* __restrict__ Bw,
                                               const float* __restrict__ bias,
                                               const float* __restrict__ res,
                                               float* __restrict__ Cout,
                                               int M, int N, int K, int epi)
{
    __shared__ float As[16][128 + 4];
    __shared__ float Bs[16][128 + 4];
    int tid = threadIdx.x;
    int row0 = blockIdx.y * 128;
    int col0 = blockIdx.x * 128;
    int tm0 = (tid / 16) * 8;
    int tn0 = (tid % 16) * 8;

    float acc[8][8];
    #pragma unroll
    for (int i = 0; i < 8; i++)
        #pragma unroll
        for (int j = 0; j < 8; j++) acc[i][j] = 0.f;

    for (int k0 = 0; k0 < K; k0 += 16) {
        #pragma unroll
        for (int i = 0; i < 2; i++) {
            int ff = tid + i * 256;          // 0..511
            int m  = ff >> 2;                // 0..127
            int kq = ff & 3;                 // 0..3
            float4 a4 = *(const float4*)(A  + (size_t)(row0 + m) * K + k0 + kq * 4);
            As[kq*4+0][m] = a4.x; As[kq*4+1][m] = a4.y; As[kq*4+2][m] = a4.z; As[kq*4+3][m] = a4.w;
            float4 b4 = *(const float4*)(Bw + (size_t)(col0 + m) * K + k0 + kq * 4);
            Bs[kq*4+0][m] = b4.x; Bs[kq*4+1][m] = b4.y; Bs[kq*4+2][m] = b4.z; Bs[kq*4+3][m] = b4.w;
        }
        __syncthreads();
        #pragma unroll
        for (int k = 0; k < 16; k++) {
            float a[8], b[8];
            #pragma unroll
            for (int i = 0; i < 8; i++) a[i] = As[k][tm0 + i];
            #pragma unroll
            for (int j = 0; j < 8; j++) b[j] = Bs[k][tn0 + j];
            #pragma unroll
            for (int i = 0; i < 8; i++)
                #pragma unroll
                for (int j = 0; j < 8; j++) acc[i][j] += a[i] * b[j];
        }
        __syncthreads();
    }

    #pragma unroll
    for (int i = 0; i < 8; i++) {
        int m = row0 + tm0 + i;
        #pragma unroll
        for (int j = 0; j < 8; j++) {
            int n = col0 + tn0 + j;
            float v = acc[i][j];
            float o;
            if (epi == EPI_NONE)      o = v + bias[n];
            else if (epi == EPI_GELU) o = gelu_f(v + bias[n]);
            else if (epi == EPI_RES)  o = res[(size_t)m * N + n] + v + bias[n];
            else /* EPI_DIST */       o = (bias[n] + res[m] - 2.f * v) * (1.f / C_);
            Cout[(size_t)m * N + n] = o;
        }
    }
}

// ---------------- fused causal attention: one block per (b,h,q-row) --------
__global__ __launch_bounds__(256) void attn_k(const float* __restrict__ qkv,
                                              float* __restrict__ y)
{
    int qi = blockIdx.x, h = blockIdx.y, b = blockIdx.z;
    int tid = threadIdx.x;
    __shared__ float qs[HD_];
    __shared__ float p[T_];
    __shared__ float red[256];

    const size_t rowstride = 3 * C_;
    const float* qrow = qkv + (size_t)(b * T_ + qi) * rowstride + h * HD_;
    if (tid < HD_) qs[tid] = qrow[tid];
    __syncthreads();

    float lmax = -INFINITY;
    for (int kk = tid; kk < T_; kk += 256) {
        float s;
        if (kk <= qi) {
            const float* krow = qkv + (size_t)(b * T_ + kk) * rowstride + C_ + h * HD_;
            float dot = 0.f;
            #pragma unroll
            for (int d = 0; d < HD_; d += 4) {
                float4 k4 = *(const float4*)(krow + d);
                dot += qs[d]*k4.x + qs[d+1]*k4.y + qs[d+2]*k4.z + qs[d+3]*k4.w;
            }
            s = dot * 0.125f;   // 1/sqrt(64)
        } else s = -INFINITY;
        p[kk] = s;
        lmax = fmaxf(lmax, s);
    }
    red[tid] = lmax; __syncthreads();
    for (int s = 128; s > 0; s >>= 1) { if (tid < s) red[tid] = fmaxf(red[tid], red[tid+s]); __syncthreads(); }
    float mx = red[0];
    __syncthreads();

    float lsum = 0.f;
    for (int kk = tid; kk < T_; kk += 256) {
        float e = expf(p[kk] - mx);   // exp(-inf)=0 for masked
        p[kk] = e;
        lsum += e;
    }
    red[tid] = lsum; __syncthreads();
    for (int s = 128; s > 0; s >>= 1) { if (tid < s) red[tid] += red[tid+s]; __syncthreads(); }
    float inv = 1.f / red[0];
    __syncthreads();

    int d = tid & 63, g = tid >> 6;   // 4 groups of 64
    float part = 0.f;
    for (int kk = g; kk <= qi; kk += 4) {
        part += p[kk] * qkv[(size_t)(b * T_ + kk) * rowstride + 2 * C_ + h * HD_ + d];
    }
    red[tid] = part; __syncthreads();
    if (g == 0) {
        float r = red[d] + red[64 + d] + red[128 + d] + red[192 + d];
        y[(size_t)(b * T_ + qi) * C_ + h * HD_ + d] = r * inv;
    }
}

// ---------------- head helpers ----------------
__global__ __launch_bounds__(256) void rowsq_k(const float* __restrict__ w, float* __restrict__ out)
{   // out[row] = sum_c w[row,c]^2 ; grid = V_
    int row = blockIdx.x, tid = threadIdx.x;
    __shared__ float red[256];
    const float* wr = w + (size_t)row * C_;
    float ls = 0.f;
    for (int i = tid; i < C_; i += 256) { float v = wr[i]; ls += v * v; }
    red[tid] = ls; __syncthreads();
    for (int s = 128; s > 0; s >>= 1) { if (tid < s) red[tid] += red[tid+s]; __syncthreads(); }
    if (tid == 0) out[row] = red[0];
}

__global__ __launch_bounds__(256) void rowmin_k(const float* __restrict__ d, float* __restrict__ dmin)
{
    int row = blockIdx.x, tid = threadIdx.x;
    __shared__ float red[256];
    const float* dr = d + (size_t)row * V_;
    float lm = 3.4e38f;
    for (int v = tid; v < V_; v += 256) lm = fminf(lm, dr[v]);
    red[tid] = lm; __syncthreads();
    for (int s = 128; s > 0; s >>= 1) { if (tid < s) red[tid] = fminf(red[tid], red[tid+s]); __syncthreads(); }
    if (tid == 0) dmin[row] = red[0];
}

__global__ __launch_bounds__(256) void rowsum_k(const float* __restrict__ d,
                                                const float* __restrict__ dmin,
                                                float* __restrict__ dsum)
{
    int row = blockIdx.x, tid = threadIdx.x;
    __shared__ float red[256];
    const float* dr = d + (size_t)row * V_;
    float mn = dmin[row];
    float ls = 0.f;
    for (int v = tid; v < V_; v += 256) {
        float r = dr[v] / mn;
        ls += exp2f(-768.f * log2f(r));
    }
    red[tid] = ls; __syncthreads();
    for (int s = 128; s > 0; s >>= 1) { if (tid < s) red[tid] += red[tid+s]; __syncthreads(); }
    if (tid == 0) dsum[row] = red[0];
}

__global__ __launch_bounds__(256) void logits_k(float* __restrict__ d,
                                                const float* __restrict__ dmin,
                                                const float* __restrict__ dsum)
{   // grid: (ceil(V/256), M); in-place on d
    int m = blockIdx.y;
    int v = blockIdx.x * 256 + threadIdx.x;
    if (v >= V_) return;
    size_t i = (size_t)m * V_ + v;
    float r = d[i] / dmin[m];
    float val = exp2f(-768.f * log2f(r));
    float prob = val / dsum[m] + (0.01f / 50304.f);
    d[i] = logf(prob);
}

// ---------------- launch ----------------
extern "C" void kernel_launch(void* const* d_in, const int* in_sizes, int n_in,
                              void* d_out, int out_size, void* d_ws, size_t ws_size,
                              hipStream_t stream)
{
    (void)in_sizes; (void)n_in; (void)out_size; (void)ws_size;
    const int*   idx    = (const int*)  d_in[0];
    const float* wte    = (const float*)d_in[1];
    const float* wpe    = (const float*)d_in[2];
    const float* ln1_w  = (const float*)d_in[3];
    const float* ln1_b  = (const float*)d_in[4];
    const float* attn_w = (const float*)d_in[5];
    const float* attn_b = (const float*)d_in[6];
    const float* proj_w = (const float*)d_in[7];
    const float* proj_b = (const float*)d_in[8];
    const float* ln2_w  = (const float*)d_in[9];
    const float* ln2_b  = (const float*)d_in[10];
    const float* fc_w   = (const float*)d_in[11];
    const float* fc_b   = (const float*)d_in[12];
    const float* fc2_w  = (const float*)d_in[13];
    const float* fc2_b  = (const float*)d_in[14];
    const float* lnf_w  = (const float*)d_in[15];
    const float* lnf_b  = (const float*)d_in[16];

    float* dout = (float*)d_out;

    float* ws = (float*)d_ws;
    float* x    = ws;                 // M*C
    float* h    = x    + (size_t)M_ * C_;      // M*C
    float* qkv  = h    + (size_t)M_ * C_;      // M*3C
    float* y    = qkv  + (size_t)M_ * 3 * C_;  // M*C
    float* hm   = y    + (size_t)M_ * C_;      // M*4C
    float* xx   = hm   + (size_t)M_ * 4 * C_;  // M
    float* ww   = xx   + M_;                   // V
    float* dmin = ww   + V_;                   // M
    float* dsum = dmin + M_;                   // M

    embed_k<<<M_, 256, 0, stream>>>(idx, wte, wpe, x);

    for (int l = 0; l < L_; l++) {
        // attention block
        ln_k<<<M_, 256, 0, stream>>>(x, ln1_w + (size_t)l*C_, ln1_b + (size_t)l*C_, h, nullptr);
        gemm_nt<<<dim3(3*C_/128, M_/128), 256, 0, stream>>>(
            h, attn_w + (size_t)l*3*C_*C_, attn_b + (size_t)l*3*C_, nullptr, qkv,
            M_, 3*C_, C_, EPI_NONE);
        attn_k<<<dim3(T_, H_, B_), 256, 0, stream>>>(qkv, y);
        gemm_nt<<<dim3(C_/128, M_/128), 256, 0, stream>>>(
            y, proj_w + (size_t)l*C_*C_, proj_b + (size_t)l*C_, x, x,
            M_, C_, C_, EPI_RES);
        // MLP block
        ln_k<<<M_, 256, 0, stream>>>(x, ln2_w + (size_t)l*C_, ln2_b + (size_t)l*C_, h, nullptr);
        gemm_nt<<<dim3(4*C_/128, M_/128), 256, 0, stream>>>(
            h, fc_w + (size_t)l*4*C_*C_, fc_b + (size_t)l*4*C_, nullptr, hm,
            M_, 4*C_, C_, EPI_GELU);
        gemm_nt<<<dim3(C_/128, M_/128), 256, 0, stream>>>(
            hm, fc2_w + (size_t)l*C_*4*C_, fc2_b + (size_t)l*C_, x, x,
            M_, C_, 4*C_, EPI_RES);
    }

    // final LN (also produces xx = row sum of squares)
    ln_k<<<M_, 256, 0, stream>>>(x, lnf_w, lnf_b, h, xx);
    // ww = row sums of squares of wte
    rowsq_k<<<V_, 256, 0, stream>>>(wte, ww);
    // d = (ww[n] + xx[m] - 2*<xf,wte_n>)/C  -> into d_out
    gemm_nt<<<dim3(V_/128, M_/128), 256, 0, stream>>>(
        h, wte, ww, xx, dout, M_, V_, C_, EPI_DIST);
    // row min, row sum of d^-768, then in-place logits
    rowmin_k<<<M_, 256, 0, stream>>>(dout, dmin);
    rowsum_k<<<M_, 256, 0, stream>>>(dout, dmin, dsum);
    logits_k<<<dim3((V_ + 255)/256, M_), 256, 0, stream>>>(dout, dmin, dsum);
}

// Round 2
// 5931.078 us; speedup vs baseline: 2.1563x; 2.1563x over previous
//
#include <hip/hip_runtime.h>
#include <hip/hip_bf16.h>
#include <math.h>

// Problem constants
#define B_  2
#define T_  512
#define C_  768
#define H_  12
#define V_  50304
#define L_  12
#define HD_ 64
#define M_  (B_*T_)          // 1024 rows of activations

#define EPI_QKV  0   // out f32 = v + bias[n]
#define EPI_GELU 1   // out bf16 = gelu(v + bias[n])
#define EPI_RES  2   // out f32 = res[m,n] + v + bias[n]
#define EPI_DIST 3   // out f32 = (bias[n] + res[m] - 2v)/C

typedef __attribute__((ext_vector_type(8))) short short8;
typedef __attribute__((ext_vector_type(4))) float f32x4;

// ---------- helpers ----------
__device__ __forceinline__ unsigned short f2bf(float f) {
    unsigned int u = __float_as_uint(f);
    unsigned int r = (u + 0x7fffu + ((u >> 16) & 1u)) >> 16;
    return (unsigned short)r;
}

__device__ __forceinline__ float gelu_f(float t) {
    return 0.5f * t * (1.0f + tanhf(0.7978845608028654f * (t + 0.044715f * t * t * t)));
}

__device__ __forceinline__ void gld_lds16(const void* g, void* l) {
    __builtin_amdgcn_global_load_lds(
        (const __attribute__((address_space(1))) unsigned int*)g,
        (__attribute__((address_space(3))) unsigned int*)l,
        16, 0, 0);
}

// ---------- f32 -> bf16 conversion (vector x4), n % 4 == 0 ----------
__global__ __launch_bounds__(256) void cvt_k(const float* __restrict__ src,
                                             unsigned short* __restrict__ dst,
                                             int n4)
{
    for (int i = blockIdx.x * 256 + threadIdx.x; i < n4; i += gridDim.x * 256) {
        float4 v = *(const float4*)(src + (size_t)i * 4);
        ushort4 o;
        o.x = f2bf(v.x); o.y = f2bf(v.y); o.z = f2bf(v.z); o.w = f2bf(v.w);
        *(ushort4*)(dst + (size_t)i * 4) = o;
    }
}

// ---------------- embedding ----------------
__global__ __launch_bounds__(256) void embed_k(const int* __restrict__ idx,
                                               const float* __restrict__ wte,
                                               const float* __restrict__ wpe,
                                               float* __restrict__ x)
{
    int row = blockIdx.x;
    int t   = row & (T_-1);
    int tok = idx[row];
    const float* wt = wte + (size_t)tok * C_;
    const float* wp = wpe + (size_t)t   * C_;
    float* xr = x + (size_t)row * C_;
    for (int i = threadIdx.x; i < C_; i += 256)
        xr[i] = wt[i] + wp[i];
}

// ---------------- layernorm: f32 in -> bf16 out (+optional sumsq) ----------
__global__ __launch_bounds__(256) void ln_k(const float* __restrict__ x,
                                            const float* __restrict__ w,
                                            const float* __restrict__ bb,
                                            unsigned short* __restrict__ out,
                                            float* __restrict__ xx_out)
{
    int row = blockIdx.x, tid = threadIdx.x;
    __shared__ float buf[C_];
    __shared__ float red[256];
    const float* xr = x + (size_t)row * C_;

    float ls = 0.f;
    for (int i = tid; i < C_; i += 256) { float v = xr[i]; buf[i] = v; ls += v; }
    red[tid] = ls; __syncthreads();
    for (int s = 128; s > 0; s >>= 1) { if (tid < s) red[tid] += red[tid+s]; __syncthreads(); }
    float mean = red[0] * (1.f / C_);
    __syncthreads();

    float lv = 0.f;
    for (int i = tid; i < C_; i += 256) { float d = buf[i] - mean; lv += d*d; }
    red[tid] = lv; __syncthreads();
    for (int s = 128; s > 0; s >>= 1) { if (tid < s) red[tid] += red[tid+s]; __syncthreads(); }
    float rstd = 1.0f / sqrtf(red[0] * (1.f / C_) + 1e-5f);
    __syncthreads();

    float lss = 0.f;
    unsigned short* orow = out + (size_t)row * C_;
    for (int i = tid; i < C_; i += 256) {
        float o = (buf[i] - mean) * rstd * w[i] + bb[i];
        orow[i] = f2bf(o);
        lss += o * o;
    }
    if (xx_out) {
        red[tid] = lss; __syncthreads();
        for (int s = 128; s > 0; s >>= 1) { if (tid < s) red[tid] += red[tid+s]; __syncthreads(); }
        if (tid == 0) xx_out[row] = red[0];
    }
}

// ---------------- bf16 MFMA NT GEMM (m97 structure) ----------------
// C[m,n] = sum_k A[m,k]*Bw[n,k]; A [M,K] bf16, Bw [N,K] bf16.
// 128x128 tile, 4 waves, 4x4 frags of mfma_f32_16x16x32_bf16, BK=32,
// global_load_lds width-16 staging, single-buffered LDS.
__global__ __launch_bounds__(256) void gemm_bf16(
    const unsigned short* __restrict__ A,
    const unsigned short* __restrict__ Bw,
    const float* __restrict__ bias,
    const float* __restrict__ res,
    float* __restrict__ outF,
    unsigned short* __restrict__ outB,
    int M, int N, int K, int epi)
{
    __shared__ unsigned short As[128 * 32];
    __shared__ unsigned short Bs[128 * 32];
    const int tid = threadIdx.x;
    const int wv = tid >> 6, ln = tid & 63;
    const int lr = ln >> 2, lk = ln & 3;   // 16 rows x 4 k-chunks per wave pass
    const int row0 = blockIdx.y * 128, col0 = blockIdx.x * 128;

    const unsigned short* gA0 = A  + (size_t)(row0 + wv*16 + lr) * K + lk*8;
    const unsigned short* gA1 = gA0 + (size_t)64 * K;
    const unsigned short* gB0 = Bw + (size_t)(col0 + wv*16 + lr) * K + lk*8;
    const unsigned short* gB1 = gB0 + (size_t)64 * K;
    unsigned short* lA0 = As + (wv*16 + lr)*32 + lk*8;
    unsigned short* lA1 = lA0 + 64*32;
    unsigned short* lB0 = Bs + (wv*16 + lr)*32 + lk*8;
    unsigned short* lB1 = lB0 + 64*32;

    const int wr = (wv >> 1) * 64, wc = (wv & 1) * 64;
    const int fr = ln & 15, qd = ln >> 4;

    f32x4 acc[4][4] = {};

    for (int k0 = 0; k0 < K; k0 += 32) {
        gld_lds16(gA0 + k0, lA0);
        gld_lds16(gA1 + k0, lA1);
        gld_lds16(gB0 + k0, lB0);
        gld_lds16(gB1 + k0, lB1);
        __syncthreads();

        short8 af[4], bfm[4];
        #pragma unroll
        for (int i = 0; i < 4; i++)
            af[i] = *(const short8*)(As + (wr + i*16 + fr)*32 + qd*8);
        #pragma unroll
        for (int j = 0; j < 4; j++)
            bfm[j] = *(const short8*)(Bs + (wc + j*16 + fr)*32 + qd*8);
        #pragma unroll
        for (int i = 0; i < 4; i++)
            #pragma unroll
            for (int j = 0; j < 4; j++)
                acc[i][j] = __builtin_amdgcn_mfma_f32_16x16x32_bf16(af[i], bfm[j], acc[i][j], 0, 0, 0);
        __syncthreads();
    }

    // epilogue: D[row = qd*4+reg (+i*16)][col = fr (+j*16)]
    #pragma unroll
    for (int i = 0; i < 4; i++) {
        #pragma unroll
        for (int j = 0; j < 4; j++) {
            int n = col0 + wc + j*16 + fr;
            float bn = bias[n];
            f32x4 v = acc[i][j];
            #pragma unroll
            for (int r = 0; r < 4; r++) {
                int m = row0 + wr + i*16 + qd*4 + r;
                float val = v[r];
                if (epi == EPI_QKV)
                    outF[(size_t)m * N + n] = val + bn;
                else if (epi == EPI_GELU)
                    outB[(size_t)m * N + n] = f2bf(gelu_f(val + bn));
                else if (epi == EPI_RES)
                    outF[(size_t)m * N + n] = res[(size_t)m * N + n] + val + bn;
                else // EPI_DIST
                    outF[(size_t)m * N + n] = (bn + res[m] - 2.f * val) * (1.f / C_);
            }
        }
    }
}

// ---------------- fused causal attention (qkv f32 in, y bf16 out) ---------
__global__ __launch_bounds__(256) void attn_k(const float* __restrict__ qkv,
                                              unsigned short* __restrict__ y)
{
    int qi = blockIdx.x, h = blockIdx.y, b = blockIdx.z;
    int tid = threadIdx.x;
    __shared__ float qs[HD_];
    __shared__ float p[T_];
    __shared__ float red[256];

    const size_t rowstride = 3 * C_;
    const float* qrow = qkv + (size_t)(b * T_ + qi) * rowstride + h * HD_;
    if (tid < HD_) qs[tid] = qrow[tid];
    __syncthreads();

    float lmax = -INFINITY;
    for (int kk = tid; kk < T_; kk += 256) {
        float s;
        if (kk <= qi) {
            const float* krow = qkv + (size_t)(b * T_ + kk) * rowstride + C_ + h * HD_;
            float dot = 0.f;
            #pragma unroll
            for (int d = 0; d < HD_; d += 4) {
                float4 k4 = *(const float4*)(krow + d);
                dot += qs[d]*k4.x + qs[d+1]*k4.y + qs[d+2]*k4.z + qs[d+3]*k4.w;
            }
            s = dot * 0.125f;
        } else s = -INFINITY;
        p[kk] = s;
        lmax = fmaxf(lmax, s);
    }
    red[tid] = lmax; __syncthreads();
    for (int s = 128; s > 0; s >>= 1) { if (tid < s) red[tid] = fmaxf(red[tid], red[tid+s]); __syncthreads(); }
    float mx = red[0];
    __syncthreads();

    float lsum = 0.f;
    for (int kk = tid; kk < T_; kk += 256) {
        float e = expf(p[kk] - mx);
        p[kk] = e;
        lsum += e;
    }
    red[tid] = lsum; __syncthreads();
    for (int s = 128; s > 0; s >>= 1) { if (tid < s) red[tid] += red[tid+s]; __syncthreads(); }
    float inv = 1.f / red[0];
    __syncthreads();

    int d = tid & 63, g = tid >> 6;
    float part = 0.f;
    for (int kk = g; kk <= qi; kk += 4) {
        part += p[kk] * qkv[(size_t)(b * T_ + kk) * rowstride + 2 * C_ + h * HD_ + d];
    }
    red[tid] = part; __syncthreads();
    if (g == 0) {
        float r = red[d] + red[64 + d] + red[128 + d] + red[192 + d];
        y[(size_t)(b * T_ + qi) * C_ + h * HD_ + d] = f2bf(r * inv);
    }
}

// ---------------- head helpers ----------------
__global__ __launch_bounds__(256) void rowsq_k(const float* __restrict__ w, float* __restrict__ out)
{
    int row = blockIdx.x, tid = threadIdx.x;
    __shared__ float red[256];
    const float* wr = w + (size_t)row * C_;
    float ls = 0.f;
    for (int i = tid; i < C_; i += 256) { float v = wr[i]; ls += v * v; }
    red[tid] = ls; __syncthreads();
    for (int s = 128; s > 0; s >>= 1) { if (tid < s) red[tid] += red[tid+s]; __syncthreads(); }
    if (tid == 0) out[row] = red[0];
}

__global__ __launch_bounds__(256) void rowmin_k(const float* __restrict__ d, float* __restrict__ dmin)
{
    int row = blockIdx.x, tid = threadIdx.x;
    __shared__ float red[256];
    const float* dr = d + (size_t)row * V_;
    float lm = 3.4e38f;
    for (int v = tid; v < V_; v += 256) lm = fminf(lm, dr[v]);
    red[tid] = lm; __syncthreads();
    for (int s = 128; s > 0; s >>= 1) { if (tid < s) red[tid] = fminf(red[tid], red[tid+s]); __syncthreads(); }
    if (tid == 0) dmin[row] = red[0];
}

__global__ __launch_bounds__(256) void rowsum_k(const float* __restrict__ d,
                                                const float* __restrict__ dmin,
                                                float* __restrict__ dsum)
{
    int row = blockIdx.x, tid = threadIdx.x;
    __shared__ float red[256];
    const float* dr = d + (size_t)row * V_;
    float mn = dmin[row];
    float ls = 0.f;
    for (int v = tid; v < V_; v += 256) {
        float r = dr[v] / mn;
        ls += exp2f(-768.f * log2f(r));
    }
    red[tid] = ls; __syncthreads();
    for (int s = 128; s > 0; s >>= 1) { if (tid < s) red[tid] += red[tid+s]; __syncthreads(); }
    if (tid == 0) dsum[row] = red[0];
}

__global__ __launch_bounds__(256) void logits_k(float* __restrict__ d,
                                                const float* __restrict__ dmin,
                                                const float* __restrict__ dsum)
{
    int m = blockIdx.y;
    int v = blockIdx.x * 256 + threadIdx.x;
    if (v >= V_) return;
    size_t i = (size_t)m * V_ + v;
    float r = d[i] / dmin[m];
    float val = exp2f(-768.f * log2f(r));
    float prob = val / dsum[m] + (0.01f / 50304.f);
    d[i] = logf(prob);
}

// ---------------- launch ----------------
static inline size_t align256(size_t x) { return (x + 255) & ~(size_t)255; }

extern "C" void kernel_launch(void* const* d_in, const int* in_sizes, int n_in,
                              void* d_out, int out_size, void* d_ws, size_t ws_size,
                              hipStream_t stream)
{
    (void)in_sizes; (void)n_in; (void)out_size; (void)ws_size;
    const int*   idx    = (const int*)  d_in[0];
    const float* wte    = (const float*)d_in[1];
    const float* wpe    = (const float*)d_in[2];
    const float* ln1_w  = (const float*)d_in[3];
    const float* ln1_b  = (const float*)d_in[4];
    const float* attn_w = (const float*)d_in[5];
    const float* attn_b = (const float*)d_in[6];
    const float* proj_w = (const float*)d_in[7];
    const float* proj_b = (const float*)d_in[8];
    const float* ln2_w  = (const float*)d_in[9];
    const float* ln2_b  = (const float*)d_in[10];
    const float* fc_w   = (const float*)d_in[11];
    const float* fc_b   = (const float*)d_in[12];
    const float* fc2_w  = (const float*)d_in[13];
    const float* fc2_b  = (const float*)d_in[14];
    const float* lnf_w  = (const float*)d_in[15];
    const float* lnf_b  = (const float*)d_in[16];

    float* dout = (float*)d_out;

    // workspace layout
    char* p = (char*)d_ws;
    size_t off = 0;
    float* x    = (float*)(p + off); off = align256(off + (size_t)M_*C_*4);
    float* qkv  = (float*)(p + off); off = align256(off + (size_t)M_*3*C_*4);
    float* xx   = (float*)(p + off); off = align256(off + (size_t)M_*4);
    float* ww   = (float*)(p + off); off = align256(off + (size_t)V_*4);
    float* dmin = (float*)(p + off); off = align256(off + (size_t)M_*4);
    float* dsum = (float*)(p + off); off = align256(off + (size_t)M_*4);
    unsigned short* h     = (unsigned short*)(p + off); off = align256(off + (size_t)M_*C_*2);
    unsigned short* y     = (unsigned short*)(p + off); off = align256(off + (size_t)M_*C_*2);
    unsigned short* hm    = (unsigned short*)(p + off); off = align256(off + (size_t)M_*4*C_*2);
    unsigned short* wte16 = (unsigned short*)(p + off); off = align256(off + (size_t)V_*C_*2);
    unsigned short* wbuf  = (unsigned short*)(p + off); off = align256(off + (size_t)9216*C_*2);

    const size_t nAttn = (size_t)3*C_*C_;    // 1769472
    const size_t nProj = (size_t)C_*C_;      //  589824
    const size_t nFc   = (size_t)4*C_*C_;    // 2359296
    const size_t nFc2  = (size_t)4*C_*C_;    // 2359296
    unsigned short* w_attn = wbuf;
    unsigned short* w_proj = w_attn + nAttn;
    unsigned short* w_fc   = w_proj + nProj;
    unsigned short* w_fc2  = w_fc   + nFc;

    // wte bf16 + ww (independent of layer loop)
    cvt_k<<<4096, 256, 0, stream>>>(wte, wte16, (int)((size_t)V_*C_/4));
    rowsq_k<<<V_, 256, 0, stream>>>(wte, ww);

    embed_k<<<M_, 256, 0, stream>>>(idx, wte, wpe, x);

    for (int l = 0; l < L_; l++) {
        // per-layer weight conversion (packed)
        cvt_k<<<1728, 256, 0, stream>>>(attn_w + (size_t)l*nAttn, w_attn, (int)(nAttn/4));
        cvt_k<<<576,  256, 0, stream>>>(proj_w + (size_t)l*nProj, w_proj, (int)(nProj/4));
        cvt_k<<<2304, 256, 0, stream>>>(fc_w   + (size_t)l*nFc,   w_fc,   (int)(nFc/4));
        cvt_k<<<2304, 256, 0, stream>>>(fc2_w  + (size_t)l*nFc2,  w_fc2,  (int)(nFc2/4));

        // attention block
        ln_k<<<M_, 256, 0, stream>>>(x, ln1_w + (size_t)l*C_, ln1_b + (size_t)l*C_, h, nullptr);
        gemm_bf16<<<dim3(3*C_/128, M_/128), 256, 0, stream>>>(
            h, w_attn, attn_b + (size_t)l*3*C_, nullptr, qkv, nullptr,
            M_, 3*C_, C_, EPI_QKV);
        attn_k<<<dim3(T_, H_, B_), 256, 0, stream>>>(qkv, y);
        gemm_bf16<<<dim3(C_/128, M_/128), 256, 0, stream>>>(
            y, w_proj, proj_b + (size_t)l*C_, x, x, nullptr,
            M_, C_, C_, EPI_RES);
        // MLP block
        ln_k<<<M_, 256, 0, stream>>>(x, ln2_w + (size_t)l*C_, ln2_b + (size_t)l*C_, h, nullptr);
        gemm_bf16<<<dim3(4*C_/128, M_/128), 256, 0, stream>>>(
            h, w_fc, fc_b + (size_t)l*4*C_, nullptr, nullptr, hm,
            M_, 4*C_, C_, EPI_GELU);
        gemm_bf16<<<dim3(C_/128, M_/128), 256, 0, stream>>>(
            hm, w_fc2, fc2_b + (size_t)l*C_, x, x, nullptr,
            M_, C_, 4*C_, EPI_RES);
    }

    // final LN (+ xx = row sum of squares of normalized output)
    ln_k<<<M_, 256, 0, stream>>>(x, lnf_w, lnf_b, h, xx);
    // distance head GEMM: d = (ww[n] + xx[m] - 2*<h, wte_n>)/C
    gemm_bf16<<<dim3(V_/128, M_/128), 256, 0, stream>>>(
        h, wte16, ww, xx, dout, nullptr,
        M_, V_, C_, EPI_DIST);
    // row min, row sum of d^-768, then in-place logits
    rowmin_k<<<M_, 256, 0, stream>>>(dout, dmin);
    rowsum_k<<<M_, 256, 0, stream>>>(dout, dmin, dsum);
    logits_k<<<dim3((V_ + 255)/256, M_), 256, 0, stream>>>(dout, dmin, dsum);
}